// Round 6
// baseline (829.101 us; speedup 1.0000x reference)
//
#include <hip/hip_runtime.h>
#include <math.h>

#define BB 16
#define NN 512
#define HH 128
#define EE 4
#define NSTEPS 5
#define ROWS (BB*NN)      // 8192
#define KDIM (NN*EE)      // 2048

typedef _Float16 f16x8 __attribute__((ext_vector_type(8)));
typedef float f32x4 __attribute__((ext_vector_type(4)));

#define MFMA(a,b,c) __builtin_amdgcn_mfma_f32_16x16x32_f16(a, b, c, 0, 0, 0)

__device__ inline void split8v(float4 u, float4 v, f16x8& hi, f16x8& lo) {
    float f[8] = {u.x, u.y, u.z, u.w, v.x, v.y, v.z, v.w};
    #pragma unroll
    for (int i = 0; i < 8; i++) {
        _Float16 h = (_Float16)f[i];
        hi[i] = h;
        lo[i] = (_Float16)(f[i] - (float)h);
    }
}

__device__ inline void split1(float v, _Float16* __restrict__ hp, _Float16* __restrict__ lp) {
    _Float16 h = (_Float16)v;
    *hp = h;
    *lp = (_Float16)(v - (float)h);
}

__device__ inline float4 f4add(float4 a, float4 b) {
    return make_float4(a.x + b.x, a.y + b.y, a.z + b.z, a.w + b.w);
}

// async global->LDS, 16B per lane. lds must be wave-uniform base; HW scatters
// lane i at base + i*16.
__device__ __forceinline__ void async16(void* lds, const void* g) {
    __builtin_amdgcn_global_load_lds(
        (const __attribute__((address_space(1))) void*)g,
        (__attribute__((address_space(3))) void*)lds,
        16, 0, 0);
}

// ---------------------------------------------------------------------------
// Prep: split-fp16 transposed weights + split of initial h = x + W1T split.
// ---------------------------------------------------------------------------
__global__ void prep_kernel(const float* __restrict__ x,
                            const float* __restrict__ W_in, const float* __restrict__ b_in,
                            const float* __restrict__ W_out, const float* __restrict__ b_out,
                            const float* __restrict__ W_z, const float* __restrict__ W_r,
                            const float* __restrict__ W_t, const float* __restrict__ W1,
                            _Float16* __restrict__ WpTh, _Float16* __restrict__ WpTl,
                            float* __restrict__ bp,
                            _Float16* __restrict__ WzrtH, _Float16* __restrict__ WzrtL,
                            _Float16* __restrict__ Wt1h, _Float16* __restrict__ Wt1l,
                            _Float16* __restrict__ hHi, _Float16* __restrict__ hLo,
                            _Float16* __restrict__ W1Th, _Float16* __restrict__ W1Tl) {
    int idx = blockIdx.x * 256 + threadIdx.x;
    if (idx < 131072) {                                  // WpT
        int c = idx >> 7, k = idx & 127;
        int io = c >> 9, cc = c & 511, e = cc >> 7, hh = cc & 127;
        const float* W = io ? W_out : W_in;
        split1(W[k * 512 + hh * 4 + e], WpTh + idx, WpTl + idx);
        if (k == 0) bp[c] = (io ? b_out : b_in)[hh * 4 + e];
    } else if (idx < 131072 + 147456) {                  // Wzrt
        int j = idx - 131072;
        int c = j / 384, k = j - c * 384;
        float v;
        if (c < 128)      v = W_z[k * 128 + c];
        else if (c < 256) v = W_r[k * 128 + (c - 128)];
        else              v = (k < 256) ? W_t[k * 128 + (c - 256)] : 0.0f;
        split1(v, WzrtH + j, WzrtL + j);
    } else if (idx < 131072 + 147456 + 16384) {          // Wt1
        int j = idx - 131072 - 147456;
        int c = j >> 7, k = j & 127;
        split1(W_t[(256 + k) * 128 + c], Wt1h + j, Wt1l + j);
    } else if (idx < 131072 + 147456 + 16384 + 1048576) { // split x -> h hi/lo
        int j = idx - 131072 - 147456 - 16384;
        split1(x[j], hHi + j, hLo + j);
    } else if (idx < 131072 + 147456 + 16384 + 1048576 + 16384) { // W1T (k<128 rows)
        int j = idx - (131072 + 147456 + 16384 + 1048576);
        int c = j >> 7, k = j & 127;
        split1(W1[k * 128 + c], W1Th + j, W1Tl + j);
    }
}

// ---------------------------------------------------------------------------
// YpT[b][c][n'] = sum_k WpT[c][k] * h[b*512+n'][k] + bp[c], split-fp16 out.
// Grid (16,4,16); block 64c x 128n, 4 waves (wave 32c x 64n).
// ---------------------------------------------------------------------------
__global__ __launch_bounds__(256) void xw_mfma(
        const _Float16* __restrict__ hHi, const _Float16* __restrict__ hLo,
        const _Float16* __restrict__ WpTh, const _Float16* __restrict__ WpTl,
        const float* __restrict__ bp,
        _Float16* __restrict__ YpTh, _Float16* __restrict__ YpTl) {
    const int tid = threadIdx.x;
    const int c0 = blockIdx.x * 64;
    const int n0 = blockIdx.y * 128;
    const int b  = blockIdx.z;
    const int w = tid >> 6, l = tid & 63;
    const int lm = l & 15, q = l >> 4;
    const int wr = (w & 1) * 32, wc = (w >> 1) * 64;
    f32x4 zero = {0.f, 0.f, 0.f, 0.f};
    f32x4 acc[2][4];
    #pragma unroll
    for (int i = 0; i < 2; i++)
        #pragma unroll
        for (int j = 0; j < 4; j++) acc[i][j] = zero;
    const size_t aoff = (size_t)(c0 + wr + lm) * 128 + q * 8;
    const size_t boff = (size_t)(b * 512 + n0 + wc + lm) * 128 + q * 8;
    #pragma unroll
    for (int ki = 0; ki < 4; ki++) {
        const int kc = ki * 32;
        f16x8 a0h = *(const f16x8*)(WpTh + aoff + kc);
        f16x8 a0l = *(const f16x8*)(WpTl + aoff + kc);
        f16x8 a1h = *(const f16x8*)(WpTh + aoff + 16 * 128 + kc);
        f16x8 a1l = *(const f16x8*)(WpTl + aoff + 16 * 128 + kc);
        #pragma unroll
        for (int ct = 0; ct < 4; ct++) {
            f16x8 bh = *(const f16x8*)(hHi + boff + (size_t)(ct * 16) * 128 + kc);
            f16x8 bl = *(const f16x8*)(hLo + boff + (size_t)(ct * 16) * 128 + kc);
            acc[0][ct] = MFMA(a0h, bh, acc[0][ct]);
            acc[0][ct] = MFMA(a0h, bl, acc[0][ct]);
            acc[0][ct] = MFMA(a0l, bh, acc[0][ct]);
            acc[1][ct] = MFMA(a1h, bh, acc[1][ct]);
            acc[1][ct] = MFMA(a1h, bl, acc[1][ct]);
            acc[1][ct] = MFMA(a1l, bh, acc[1][ct]);
        }
    }
    #pragma unroll
    for (int rg = 0; rg < 2; rg++)
        #pragma unroll
        for (int rr = 0; rr < 4; rr++) {
            int c = c0 + wr + rg * 16 + q * 4 + rr;
            float bias = bp[c];
            size_t d = ((size_t)b * 1024 + c) * 512 + n0 + wc + lm;
            #pragma unroll
            for (int ct = 0; ct < 4; ct++) {
                float v = acc[rg][ct][rr] + bias;
                split1(v, YpTh + d + ct * 16, YpTl + d + ct * 16);
            }
        }
}

// ---------------------------------------------------------------------------
// Einsum, v6 = v5 structure with e-pair merge (kz 4 -> ez 2, K=1024 in-acc).
// Each block: (b, io, ez), n-tile 128 x h 128, K = 2 x 512 as 32 chunks of 32
// (first 16 chunks e=2ez, next 16 e=2ez+1; Y slab advances by 128 rows).
// 512-thread blocks (8 waves: 4 n-rowgroups x 2 h-colgroups); m staged once
// per block via global_load_lds; Y L2 traffic unchanged from v5 (4 blocks
// per slab, the variable R4 proved matters). Apart halves to 2 ez-slices
// (WRITE 33.5 -> 16.8 MB); msg_reduce is deleted (gate_gemm1 sums slices).
// LDS: per buffer m [128][32] fp32 16 KB + Y [128][64] f16 16 KB, x2 = 64 KB.
// Counted vmcnt(4) depth-1, one sched_barrier after s_barrier (rule 18),
// XOR-swizzle both tiles via pre-swizzled source (0 conflicts, R1/R3/R4).
// 256 blocks; the 4 blocks sharing a Y slab have equal wg%8 -> same XCD.
// ---------------------------------------------------------------------------
__global__ __launch_bounds__(512, 4) void msg_mfma(const float* __restrict__ m,
        const _Float16* __restrict__ YpTh, const _Float16* __restrict__ YpTl,
        float* __restrict__ Apart) {
    __shared__ float    mlds[2][128 * 32];    // 16 KB per buffer
    __shared__ _Float16 ylds[2][128 * 64];    // 16 KB per buffer: row = [32 hi | 32 lo]

    const int tid = threadIdx.x;
    const int w = tid >> 6, l = tid & 63;
    const int lm = l & 15, q = l >> 4;
    const int wr = (w & 3) * 32;              // 4 n-row groups
    const int wc = (w >> 2) * 64;             // 2 h-col groups

    // XCD-aware decode of flat blockIdx.x in [0,256)
    const int wg = blockIdx.x;
    const int xcd = wg & 7;
    const int t4  = (wg >> 3) & 3;            // n-tile within group
    const int gi  = wg >> 5;                  // [0,8) group-within-xcd
    const int g   = gi * 8 + xcd;             // [0,64) = (biz, ez)
    const int ez  = g & 1, biz = g >> 1;
    const int b = biz >> 1, io = biz & 1;
    const int n0 = t4 * 128;

    const float*    mg  = m    + (size_t)(b * 512 + n0) * 4096 + io * 2048 + ez * 1024;
    const _Float16* yhg = YpTh + (size_t)(b * 1024 + io * 512 + ez * 256) * 512;
    const _Float16* ylg = YpTl + (size_t)(b * 1024 + io * 512 + ez * 256) * 512;

    f32x4 zero = {0.f, 0.f, 0.f, 0.f};
    f32x4 acc[2][4];
    #pragma unroll
    for (int i = 0; i < 2; i++)
        #pragma unroll
        for (int j = 0; j < 4; j++) acc[i][j] = zero;

    // stage K-chunk (eee,kt) into buffer buf: 4 glds per wave (2 m + 2 Y)
    #define STAGE(buf, eee, kt) do {                                           \
        const size_t moff = (size_t)(eee) * 512 + (size_t)(kt) * 32;           \
        const size_t yoff = (size_t)(eee) * 65536 + (size_t)(kt) * 32;         \
        _Pragma("unroll")                                                      \
        for (int j = 0; j < 2; j++) {      /* m: 128 rows x 128B */            \
            int gi2 = (w * 2 + j) * 64 + l;                                    \
            int r = gi2 >> 3, pg = gi2 & 7;                                    \
            int lg = pg ^ (r & 7);                                             \
            async16(&mlds[buf][(w * 2 + j) * 256],                             \
                    mg + (size_t)r * 4096 + moff + lg * 4);                    \
        }                                                                      \
        _Pragma("unroll")                                                      \
        for (int j = 0; j < 2; j++) {      /* Y: 128 rows x 128B (hi|lo) */    \
            int gi2 = (w * 2 + j) * 64 + l;                                    \
            int r = gi2 >> 3, pg = gi2 & 7;                                    \
            int lg = pg ^ (r & 7);                                             \
            const _Float16* src = (lg < 4 ? yhg : ylg)                         \
                + (size_t)r * 512 + yoff + (lg & 3) * 8;                       \
            async16(&ylds[buf][(w * 2 + j) * 512], src);                       \
        }                                                                      \
    } while (0)

    #define COMPUTE(buf) do {                                                  \
        f16x8 ah[2], al[2];                                                    \
        _Pragma("unroll")                                                      \
        for (int rg = 0; rg < 2; rg++) {                                       \
            int r = wr + rg * 16 + lm, sw = r & 7;                             \
            const float* mrow = &mlds[buf][r * 32];                            \
            float4 u = *(const float4*)(mrow + (((2 * q) ^ sw) * 4));          \
            float4 v = *(const float4*)(mrow + (((2 * q + 1) ^ sw) * 4));      \
            split8v(u, v, ah[rg], al[rg]);                                     \
        }                                                                      \
        _Pragma("unroll")                                                      \
        for (int ct = 0; ct < 4; ct++) {                                       \
            int r = wc + ct * 16 + lm, sw = r & 7;                             \
            const _Float16* yrow = &ylds[buf][r * 64];                         \
            f16x8 bh = *(const f16x8*)(yrow + ((q ^ sw) * 8));                 \
            f16x8 bl = *(const f16x8*)(yrow + (((4 + q) ^ sw) * 8));           \
            acc[0][ct] = MFMA(ah[0], bh, acc[0][ct]);                          \
            acc[0][ct] = MFMA(ah[0], bl, acc[0][ct]);                          \
            acc[0][ct] = MFMA(al[0], bh, acc[0][ct]);                          \
            acc[1][ct] = MFMA(ah[1], bh, acc[1][ct]);                          \
            acc[1][ct] = MFMA(ah[1], bl, acc[1][ct]);                          \
            acc[1][ct] = MFMA(al[1], bh, acc[1][ct]);                          \
        }                                                                      \
    } while (0)

    // prologue: chunk 0 in flight (4 glds/wave)
    STAGE(0, 0, 0);
    #pragma unroll
    for (int t = 0; t < 32; t++) {
        if (t < 31) {
            const int t2 = t + 1;
            STAGE(t2 & 1, t2 >> 4, t2 & 15);   // prefetch chunk t+1 (WAR safe:
                                               // buf readers done at last barrier)
            asm volatile("s_waitcnt vmcnt(4)" ::: "memory");   // drain chunk t only
        } else {
            asm volatile("s_waitcnt vmcnt(0)" ::: "memory");
        }
        __builtin_amdgcn_s_barrier();        // all waves' chunk-t data in LDS
        __builtin_amdgcn_sched_barrier(0);   // don't hoist ds_read above wait
        COMPUTE(t & 1);
        __builtin_amdgcn_s_barrier();        // readers done before next overwrite
    }
    #undef STAGE
    #undef COMPUTE

    float* Ap = Apart + (((size_t)(ez * 32 + biz) * 512) + n0 + wr) * 128 + wc;
    #pragma unroll
    for (int rg = 0; rg < 2; rg++)
        #pragma unroll
        for (int ct = 0; ct < 4; ct++)
            #pragma unroll
            for (int rr = 0; rr < 4; rr++)
                Ap[(size_t)(rg * 16 + q * 4 + rr) * 128 + ct * 16 + lm] = acc[rg][ct][rr];
}

// ---------------------------------------------------------------------------
// Gate GEMM 1 (v2, reduce fused): ZRT(8192x384) = [Ain|Aout|h] @ Wzrt^T.
// A-operand (ph 0/1) is built on the fly from the 2 ez-slices of Apart:
// sum fp32 -> split8v in-reg (bit-identical to the old reduce+split+reload).
// Grid (128, 3); block 64r x 128c, wave 32r x 64c.
// y==1 (r columns): fused gate_elem epilogue — r = sigma(.+b_r), write
// split(r*h) to RH instead of ZRT (r cols are never re-read).
// ---------------------------------------------------------------------------
__global__ __launch_bounds__(256) void gate_gemm1(
        const float* __restrict__ Apart,
        const _Float16* __restrict__ hHi, const _Float16* __restrict__ hLo,
        const _Float16* __restrict__ WzrtH, const _Float16* __restrict__ WzrtL,
        const float* __restrict__ hcur, const float* __restrict__ b_r,
        float* __restrict__ ZRT,
        _Float16* __restrict__ RHh, _Float16* __restrict__ RHl) {
    const size_t SL2 = (size_t)32 * 512 * 128;    // ez-slice stride
    const int tid = threadIdx.x;
    const int row0 = blockIdx.x * 64;
    const int c0 = blockIdx.y * 128;
    const int w = tid >> 6, l = tid & 63;
    const int lm = l & 15, q = l >> 4;
    const int wr = (w & 1) * 32, wc = (w >> 1) * 64;
    const size_t rA0 = (size_t)(row0 + wr + lm) * 128 + q * 8;
    const size_t rA1 = rA0 + 16 * 128;
    const int bb2 = (row0 >> 9) * 2;               // b*2 (row0 64-aligned, no b-cross)
    const int nn  = (row0 & 511) + wr + lm;        // n within batch, row-frag 0
    f32x4 zero = {0.f, 0.f, 0.f, 0.f};
    f32x4 acc[2][4];
    #pragma unroll
    for (int i = 0; i < 2; i++)
        #pragma unroll
        for (int j = 0; j < 4; j++) acc[i][j] = zero;
    const size_t woff = (size_t)(c0 + wc + lm) * 384 + q * 8;
    #pragma unroll
    for (int ph = 0; ph < 3; ph++) {
        #pragma unroll
        for (int ki = 0; ki < 4; ki++) {
            const int kc = ki * 32;
            f16x8 a0h, a0l, a1h, a1l;
            if (ph < 2) {
                const float* A = Apart + ((size_t)(bb2 + ph) * 512 + nn) * 128 + q * 8 + kc;
                float4 u0 = f4add(*(const float4*)A,       *(const float4*)(A + SL2));
                float4 u1 = f4add(*(const float4*)(A + 4), *(const float4*)(A + SL2 + 4));
                split8v(u0, u1, a0h, a0l);
                const float* B = A + 16 * 128;
                float4 v0 = f4add(*(const float4*)B,       *(const float4*)(B + SL2));
                float4 v1 = f4add(*(const float4*)(B + 4), *(const float4*)(B + SL2 + 4));
                split8v(v0, v1, a1h, a1l);
            } else {
                a0h = *(const f16x8*)(hHi + rA0 + kc);
                a0l = *(const f16x8*)(hLo + rA0 + kc);
                a1h = *(const f16x8*)(hHi + rA1 + kc);
                a1l = *(const f16x8*)(hLo + rA1 + kc);
            }
            const int kg = ph * 128 + kc;
            #pragma unroll
            for (int ct = 0; ct < 4; ct++) {
                f16x8 bh = *(const f16x8*)(WzrtH + woff + (size_t)(ct * 16) * 384 + kg);
                f16x8 bl = *(const f16x8*)(WzrtL + woff + (size_t)(ct * 16) * 384 + kg);
                acc[0][ct] = MFMA(a0h, bh, acc[0][ct]);
                acc[0][ct] = MFMA(a0h, bl, acc[0][ct]);
                acc[0][ct] = MFMA(a0l, bh, acc[0][ct]);
                acc[1][ct] = MFMA(a1h, bh, acc[1][ct]);
                acc[1][ct] = MFMA(a1h, bl, acc[1][ct]);
                acc[1][ct] = MFMA(a1l, bh, acc[1][ct]);
            }
        }
    }
    if (blockIdx.y == 1) {
        // fused gate_elem: local col (wc+ct*16+lm) is the r/h column index
        #pragma unroll
        for (int rg = 0; rg < 2; rg++)
            #pragma unroll
            for (int ct = 0; ct < 4; ct++)
                #pragma unroll
                for (int rr = 0; rr < 4; rr++) {
                    int grow = row0 + wr + rg * 16 + q * 4 + rr;
                    int col = wc + ct * 16 + lm;
                    float rp = acc[rg][ct][rr] + b_r[col];
                    float r = 1.0f / (1.0f + expf(-rp));
                    size_t d = (size_t)grow * 128 + col;
                    split1(r * hcur[d], RHh + d, RHl + d);
                }
    } else {
        #pragma unroll
        for (int rg = 0; rg < 2; rg++)
            #pragma unroll
            for (int ct = 0; ct < 4; ct++)
                #pragma unroll
                for (int rr = 0; rr < 4; rr++)
                    ZRT[(size_t)(row0 + wr + rg * 16 + q * 4 + rr) * 384 + c0 + wc + ct * 16 + lm] =
                        acc[rg][ct][rr];
    }
}

// ---------------------------------------------------------------------------
// Gate GEMM 2 + GRU epilogue.
// ---------------------------------------------------------------------------
__global__ __launch_bounds__(256) void gate_gemm2(
        const _Float16* __restrict__ RHh, const _Float16* __restrict__ RHl,
        const _Float16* __restrict__ Wt1h, const _Float16* __restrict__ Wt1l,
        const float* __restrict__ ZRT, const float* __restrict__ hcur,
        const float* __restrict__ b_z, const float* __restrict__ b_t,
        float* __restrict__ hnF, _Float16* __restrict__ hnH, _Float16* __restrict__ hnL) {
    const int tid = threadIdx.x;
    const int row0 = blockIdx.x * 32;
    const int w = tid >> 6, l = tid & 63;
    const int lm = l & 15, q = l >> 4;
    const int wr = (w & 1) * 16, wc = (w >> 1) * 64;
    f32x4 zero = {0.f, 0.f, 0.f, 0.f};
    f32x4 acc[4] = {zero, zero, zero, zero};
    const size_t aoff = (size_t)(row0 + wr + lm) * 128 + q * 8;
    const size_t woff = (size_t)(wc + lm) * 128 + q * 8;
    #pragma unroll
    for (int ki = 0; ki < 4; ki++) {
        const int kc = ki * 32;
        f16x8 ah = *(const f16x8*)(RHh + aoff + kc);
        f16x8 al = *(const f16x8*)(RHl + aoff + kc);
        #pragma unroll
        for (int ct = 0; ct < 4; ct++) {
            f16x8 bh = *(const f16x8*)(Wt1h + woff + (size_t)(ct * 16) * 128 + kc);
            f16x8 bl = *(const f16x8*)(Wt1l + woff + (size_t)(ct * 16) * 128 + kc);
            acc[ct] = MFMA(ah, bh, acc[ct]);
            acc[ct] = MFMA(ah, bl, acc[ct]);
            acc[ct] = MFMA(al, bh, acc[ct]);
        }
    }
    #pragma unroll
    for (int ct = 0; ct < 4; ct++)
        #pragma unroll
        for (int rr = 0; rr < 4; rr++) {
            int grow = row0 + wr + q * 4 + rr;
            int col = wc + ct * 16 + lm;
            float tp = acc[ct][rr] + ZRT[(size_t)grow * 384 + 256 + col] + b_t[col];
            float hhat = tanhf(tp);
            float zp = ZRT[(size_t)grow * 384 + col] + b_z[col];
            float z = 1.0f / (1.0f + expf(-zp));
            float hv = hcur[(size_t)grow * 128 + col];
            float hn = (1.0f - z) * hv + z * hhat;
            size_t d = (size_t)grow * 128 + col;
            hnF[d] = hn;
            split1(hn, hnH + d, hnL + d);
        }
}

// ---------------------------------------------------------------------------
// MFMA readout: feat = tanh([h|a] @ W1 + b1); out = feat@W2 + b2.
// ---------------------------------------------------------------------------
__global__ __launch_bounds__(256) void out_mfma(
        const _Float16* __restrict__ hH, const _Float16* __restrict__ hL,
        const _Float16* __restrict__ W1Th, const _Float16* __restrict__ W1Tl,
        const float* __restrict__ W1, const float* __restrict__ a,
        const float* __restrict__ b1, const float* __restrict__ W2,
        const float* __restrict__ b2, float* __restrict__ out) {
    __shared__ float red[4][16];
    const int tid = threadIdx.x;
    const int row0 = blockIdx.x * 32;
    const int w = tid >> 6, l = tid & 63;
    const int lm = l & 15, q = l >> 4;
    const int wr = (w & 1) * 16, wc = (w >> 1) * 64;
    f32x4 zero = {0.f, 0.f, 0.f, 0.f};
    f32x4 acc[4] = {zero, zero, zero, zero};
    const size_t aoff = (size_t)(row0 + wr + lm) * 128 + q * 8;
    const size_t woff = (size_t)(wc + lm) * 128 + q * 8;
    #pragma unroll
    for (int ki = 0; ki < 4; ki++) {
        const int kc = ki * 32;
        f16x8 ah = *(const f16x8*)(hH + aoff + kc);
        f16x8 al = *(const f16x8*)(hL + aoff + kc);
        #pragma unroll
        for (int ct = 0; ct < 4; ct++) {
            f16x8 bh = *(const f16x8*)(W1Th + woff + (size_t)(ct * 16) * 128 + kc);
            f16x8 bl = *(const f16x8*)(W1Tl + woff + (size_t)(ct * 16) * 128 + kc);
            acc[ct] = MFMA(ah, bh, acc[ct]);
            acc[ct] = MFMA(ah, bl, acc[ct]);
            acc[ct] = MFMA(al, bh, acc[ct]);
        }
    }
    float psum[4] = {0.f, 0.f, 0.f, 0.f};
    #pragma unroll
    for (int ct = 0; ct < 4; ct++) {
        int col = wc + ct * 16 + lm;
        float w2v = W2[col];
        float w1last = W1[128 * 128 + col];
        float b1v = b1[col];
        #pragma unroll
        for (int rr = 0; rr < 4; rr++) {
            int grow = row0 + wr + q * 4 + rr;
            float pre = acc[ct][rr] + a[grow] * w1last + b1v;
            psum[rr] += tanhf(pre) * w2v;
        }
    }
    #pragma unroll
    for (int rr = 0; rr < 4; rr++) {
        float p = psum[rr];
        p += __shfl_xor(p, 1, 64);
        p += __shfl_xor(p, 2, 64);
        p += __shfl_xor(p, 4, 64);
        p += __shfl_xor(p, 8, 64);
        if (lm == 0) red[w][q * 4 + rr] = p;
    }
    __syncthreads();
    if (tid < 32) {
        int r = tid;
        int wsel = (r >> 4) & 1;              // rows 0-15 -> waves 0&2, 16-31 -> 1&3
        out[row0 + r] = red[wsel][r & 15] + red[wsel + 2][r & 15] + b2[0];
    }
}

// ---------------------------------------------------------------------------
extern "C" void kernel_launch(void* const* d_in, const int* in_sizes, int n_in,
                              void* d_out, int out_size, void* d_ws, size_t ws_size,
                              hipStream_t stream) {
    const float* x    = (const float*)d_in[0];
    const float* a    = (const float*)d_in[1];
    const float* m    = (const float*)d_in[2];
    const float* W_in = (const float*)d_in[3];
    const float* b_in = (const float*)d_in[4];
    const float* W_out= (const float*)d_in[5];
    const float* b_out= (const float*)d_in[6];
    const float* W_z  = (const float*)d_in[7];
    const float* b_z  = (const float*)d_in[8];
    const float* W_r  = (const float*)d_in[9];
    const float* b_r  = (const float*)d_in[10];
    const float* W_t  = (const float*)d_in[11];
    const float* b_t  = (const float*)d_in[12];
    const float* W1   = (const float*)d_in[13];
    const float* b1   = (const float*)d_in[14];
    const float* W2   = (const float*)d_in[15];
    const float* b2   = (const float*)d_in[16];
    float* out = (float*)d_out;

    char* p = (char*)d_ws;
    _Float16* WpTh  = (_Float16*)p; p += 262144;
    _Float16* WpTl  = (_Float16*)p; p += 262144;
    float*    bp    = (float*)p;    p += 4096;
    _Float16* WzrtH = (_Float16*)p; p += 294912;
    _Float16* WzrtL = (_Float16*)p; p += 294912;
    _Float16* Wt1h  = (_Float16*)p; p += 32768;
    _Float16* Wt1l  = (_Float16*)p; p += 32768;
    _Float16* W1Th  = (_Float16*)p; p += 32768;
    _Float16* W1Tl  = (_Float16*)p; p += 32768;
    _Float16* YpTh  = (_Float16*)p; p += 16777216;
    _Float16* YpTl  = (_Float16*)p; p += 16777216;
    _Float16* RHh   = (_Float16*)p; p += 2097152;
    _Float16* RHl   = (_Float16*)p; p += 2097152;
    float*    ZRT   = (float*)p;    p += 12582912;
    float*    hA    = (float*)p;    p += 4194304;
    float*    hB    = (float*)p;    p += 4194304;
    _Float16* hHiA  = (_Float16*)p; p += 2097152;
    _Float16* hLoA  = (_Float16*)p; p += 2097152;
    _Float16* hHiB  = (_Float16*)p; p += 2097152;
    _Float16* hLoB  = (_Float16*)p; p += 2097152;
    float*    Apart = (float*)p;    p += 16777216;   // 2 ez-slices

    prep_kernel<<<5312, 256, 0, stream>>>(x, W_in, b_in, W_out, b_out, W_z, W_r, W_t,
                                          W1, WpTh, WpTl, bp, WzrtH, WzrtL, Wt1h, Wt1l,
                                          hHiA, hLoA, W1Th, W1Tl);

    const float* curF = x;
    const _Float16 *curH = hHiA, *curL = hLoA;
    for (int s = 0; s < NSTEPS; s++) {
        float*    nF = (s & 1) ? hB : hA;
        _Float16* nH = (s & 1) ? hHiA : hHiB;
        _Float16* nL = (s & 1) ? hLoA : hLoB;
        xw_mfma<<<dim3(16, 4, 16), 256, 0, stream>>>(curH, curL, WpTh, WpTl, bp, YpTh, YpTl);
        msg_mfma<<<dim3(256), 512, 0, stream>>>(m, YpTh, YpTl, Apart);
        gate_gemm1<<<dim3(128, 3), 256, 0, stream>>>(Apart, curH, curL, WzrtH, WzrtL,
                                                     curF, b_r, ZRT, RHh, RHl);
        gate_gemm2<<<256, 256, 0, stream>>>(RHh, RHl, Wt1h, Wt1l, ZRT, curF,
                                            b_z, b_t, nF, nH, nL);
        curF = nF; curH = nH; curL = nL;
    }
    out_mfma<<<256, 256, 0, stream>>>(curH, curL, W1Th, W1Tl, W1, a, b1, W2, b2, out);
}

// Round 7
// 755.931 us; speedup vs baseline: 1.0968x; 1.0968x over previous
//
#include <hip/hip_runtime.h>
#include <math.h>

#define BB 16
#define NN 512
#define HH 128
#define EE 4
#define NSTEPS 5
#define ROWS (BB*NN)      // 8192
#define KDIM (NN*EE)      // 2048

typedef _Float16 f16x8 __attribute__((ext_vector_type(8)));
typedef float f32x4 __attribute__((ext_vector_type(4)));

#define MFMA(a,b,c) __builtin_amdgcn_mfma_f32_16x16x32_f16(a, b, c, 0, 0, 0)

__device__ inline void split8v(float4 u, float4 v, f16x8& hi, f16x8& lo) {
    float f[8] = {u.x, u.y, u.z, u.w, v.x, v.y, v.z, v.w};
    #pragma unroll
    for (int i = 0; i < 8; i++) {
        _Float16 h = (_Float16)f[i];
        hi[i] = h;
        lo[i] = (_Float16)(f[i] - (float)h);
    }
}

__device__ inline void split1(float v, _Float16* __restrict__ hp, _Float16* __restrict__ lp) {
    _Float16 h = (_Float16)v;
    *hp = h;
    *lp = (_Float16)(v - (float)h);
}

// async global->LDS, 16B per lane. lds must be wave-uniform base; HW scatters
// lane i at base + i*16.
__device__ __forceinline__ void async16(void* lds, const void* g) {
    __builtin_amdgcn_global_load_lds(
        (const __attribute__((address_space(1))) void*)g,
        (__attribute__((address_space(3))) void*)lds,
        16, 0, 0);
}

// ---------------------------------------------------------------------------
// Prep: split-fp16 transposed weights + split of initial h = x + W1T split.
// ---------------------------------------------------------------------------
__global__ void prep_kernel(const float* __restrict__ x,
                            const float* __restrict__ W_in, const float* __restrict__ b_in,
                            const float* __restrict__ W_out, const float* __restrict__ b_out,
                            const float* __restrict__ W_z, const float* __restrict__ W_r,
                            const float* __restrict__ W_t, const float* __restrict__ W1,
                            _Float16* __restrict__ WpTh, _Float16* __restrict__ WpTl,
                            float* __restrict__ bp,
                            _Float16* __restrict__ WzrtH, _Float16* __restrict__ WzrtL,
                            _Float16* __restrict__ Wt1h, _Float16* __restrict__ Wt1l,
                            _Float16* __restrict__ hHi, _Float16* __restrict__ hLo,
                            _Float16* __restrict__ W1Th, _Float16* __restrict__ W1Tl) {
    int idx = blockIdx.x * 256 + threadIdx.x;
    if (idx < 131072) {                                  // WpT
        int c = idx >> 7, k = idx & 127;
        int io = c >> 9, cc = c & 511, e = cc >> 7, hh = cc & 127;
        const float* W = io ? W_out : W_in;
        split1(W[k * 512 + hh * 4 + e], WpTh + idx, WpTl + idx);
        if (k == 0) bp[c] = (io ? b_out : b_in)[hh * 4 + e];
    } else if (idx < 131072 + 147456) {                  // Wzrt
        int j = idx - 131072;
        int c = j / 384, k = j - c * 384;
        float v;
        if (c < 128)      v = W_z[k * 128 + c];
        else if (c < 256) v = W_r[k * 128 + (c - 128)];
        else              v = (k < 256) ? W_t[k * 128 + (c - 256)] : 0.0f;
        split1(v, WzrtH + j, WzrtL + j);
    } else if (idx < 131072 + 147456 + 16384) {          // Wt1
        int j = idx - 131072 - 147456;
        int c = j >> 7, k = j & 127;
        split1(W_t[(256 + k) * 128 + c], Wt1h + j, Wt1l + j);
    } else if (idx < 131072 + 147456 + 16384 + 1048576) { // split x -> h hi/lo
        int j = idx - 131072 - 147456 - 16384;
        split1(x[j], hHi + j, hLo + j);
    } else if (idx < 131072 + 147456 + 16384 + 1048576 + 16384) { // W1T (k<128 rows)
        int j = idx - (131072 + 147456 + 16384 + 1048576);
        int c = j >> 7, k = j & 127;
        split1(W1[k * 128 + c], W1Th + j, W1Tl + j);
    }
}

// ---------------------------------------------------------------------------
// YpT[b][c][n'] = sum_k WpT[c][k] * h[b*512+n'][k] + bp[c], split-fp16 out.
// Grid (16,4,16); block 64c x 128n, 4 waves (wave 32c x 64n).
// ---------------------------------------------------------------------------
__global__ __launch_bounds__(256) void xw_mfma(
        const _Float16* __restrict__ hHi, const _Float16* __restrict__ hLo,
        const _Float16* __restrict__ WpTh, const _Float16* __restrict__ WpTl,
        const float* __restrict__ bp,
        _Float16* __restrict__ YpTh, _Float16* __restrict__ YpTl) {
    const int tid = threadIdx.x;
    const int c0 = blockIdx.x * 64;
    const int n0 = blockIdx.y * 128;
    const int b  = blockIdx.z;
    const int w = tid >> 6, l = tid & 63;
    const int lm = l & 15, q = l >> 4;
    const int wr = (w & 1) * 32, wc = (w >> 1) * 64;
    f32x4 zero = {0.f, 0.f, 0.f, 0.f};
    f32x4 acc[2][4];
    #pragma unroll
    for (int i = 0; i < 2; i++)
        #pragma unroll
        for (int j = 0; j < 4; j++) acc[i][j] = zero;
    const size_t aoff = (size_t)(c0 + wr + lm) * 128 + q * 8;
    const size_t boff = (size_t)(b * 512 + n0 + wc + lm) * 128 + q * 8;
    #pragma unroll
    for (int ki = 0; ki < 4; ki++) {
        const int kc = ki * 32;
        f16x8 a0h = *(const f16x8*)(WpTh + aoff + kc);
        f16x8 a0l = *(const f16x8*)(WpTl + aoff + kc);
        f16x8 a1h = *(const f16x8*)(WpTh + aoff + 16 * 128 + kc);
        f16x8 a1l = *(const f16x8*)(WpTl + aoff + 16 * 128 + kc);
        #pragma unroll
        for (int ct = 0; ct < 4; ct++) {
            f16x8 bh = *(const f16x8*)(hHi + boff + (size_t)(ct * 16) * 128 + kc);
            f16x8 bl = *(const f16x8*)(hLo + boff + (size_t)(ct * 16) * 128 + kc);
            acc[0][ct] = MFMA(a0h, bh, acc[0][ct]);
            acc[0][ct] = MFMA(a0h, bl, acc[0][ct]);
            acc[0][ct] = MFMA(a0l, bh, acc[0][ct]);
            acc[1][ct] = MFMA(a1h, bh, acc[1][ct]);
            acc[1][ct] = MFMA(a1h, bl, acc[1][ct]);
            acc[1][ct] = MFMA(a1l, bh, acc[1][ct]);
        }
    }
    #pragma unroll
    for (int rg = 0; rg < 2; rg++)
        #pragma unroll
        for (int rr = 0; rr < 4; rr++) {
            int c = c0 + wr + rg * 16 + q * 4 + rr;
            float bias = bp[c];
            size_t d = ((size_t)b * 1024 + c) * 512 + n0 + wc + lm;
            #pragma unroll
            for (int ct = 0; ct < 4; ct++) {
                float v = acc[rg][ct][rr] + bias;
                split1(v, YpTh + d + ct * 16, YpTl + d + ct * 16);
            }
        }
}

// ---------------------------------------------------------------------------
// Einsum (v5, the 787-µs config, restored verbatim). Each block: (b, io, kz),
// n-tile 128 x h 128, K = 512 as 16 chunks of 32. 512-thread blocks (8 waves:
// 4 n-rowgroups x 2 h-colgroups); m staged once per block via global_load_lds;
// LDS: per buffer m [128][32] fp32 16 KB + Y [128][64] f16 16 KB, x2 = 64 KB
// -> 2 blocks/CU, 16 waves/CU, 512 blocks = 1 round. Counted vmcnt(4)
// depth-1, one sched_barrier after s_barrier, XOR-swizzle both tiles via
// pre-swizzled source (0 conflicts). 4 blocks/Y-slab share wg%8 -> same XCD.
// ---------------------------------------------------------------------------
__global__ __launch_bounds__(512, 4) void msg_mfma(const float* __restrict__ m,
        const _Float16* __restrict__ YpTh, const _Float16* __restrict__ YpTl,
        float* __restrict__ Apart) {
    __shared__ float    mlds[2][128 * 32];    // 16 KB per buffer
    __shared__ _Float16 ylds[2][128 * 64];    // 16 KB per buffer: row = [32 hi | 32 lo]

    const int tid = threadIdx.x;
    const int w = tid >> 6, l = tid & 63;
    const int lm = l & 15, q = l >> 4;
    const int wr = (w & 3) * 32;              // 4 n-row groups
    const int wc = (w >> 2) * 64;             // 2 h-col groups

    // XCD-aware decode of flat blockIdx.x in [0,512)
    const int wg = blockIdx.x;
    const int xcd = wg & 7;
    const int s8  = wg >> 3;          // [0,64)
    const int gi  = s8 >> 2;          // [0,16) group-within-xcd
    const int t4  = s8 & 3;           // n-tile within group
    const int g   = gi * 8 + xcd;     // [0,128) = (biz, kz)
    const int kz  = g & 3;
    const int biz = g >> 2;
    const int b = biz >> 1, io = biz & 1;
    const int n0 = t4 * 128;

    const float*    mg  = m    + (size_t)(b * 512 + n0) * 4096 + io * 2048 + kz * 512;
    const _Float16* yhg = YpTh + (size_t)(b * 1024 + io * 512 + kz * 128) * 512;
    const _Float16* ylg = YpTl + (size_t)(b * 1024 + io * 512 + kz * 128) * 512;

    f32x4 zero = {0.f, 0.f, 0.f, 0.f};
    f32x4 acc[2][4];
    #pragma unroll
    for (int i = 0; i < 2; i++)
        #pragma unroll
        for (int j = 0; j < 4; j++) acc[i][j] = zero;

    // stage K-chunk kt into buffer buf: 4 glds per wave (2 m + 2 Y)
    #define STAGE(buf, kt) do {                                                \
        _Pragma("unroll")                                                      \
        for (int j = 0; j < 2; j++) {      /* m: 128 rows x 128B */            \
            int gi2 = (w * 2 + j) * 64 + l;                                    \
            int r = gi2 >> 3, pg = gi2 & 7;                                    \
            int lg = pg ^ (r & 7);                                             \
            async16(&mlds[buf][(w * 2 + j) * 256],                             \
                    mg + (size_t)r * 4096 + (size_t)(kt) * 32 + lg * 4);       \
        }                                                                      \
        _Pragma("unroll")                                                      \
        for (int j = 0; j < 2; j++) {      /* Y: 128 rows x 128B (hi|lo) */    \
            int gi2 = (w * 2 + j) * 64 + l;                                    \
            int r = gi2 >> 3, pg = gi2 & 7;                                    \
            int lg = pg ^ (r & 7);                                             \
            const _Float16* src = (lg < 4 ? yhg : ylg)                         \
                + (size_t)r * 512 + (size_t)(kt) * 32 + (lg & 3) * 8;          \
            async16(&ylds[buf][(w * 2 + j) * 512], src);                       \
        }                                                                      \
    } while (0)

    #define COMPUTE(buf) do {                                                  \
        f16x8 ah[2], al[2];                                                    \
        _Pragma("unroll")                                                      \
        for (int rg = 0; rg < 2; rg++) {                                       \
            int r = wr + rg * 16 + lm, sw = r & 7;                             \
            const float* mrow = &mlds[buf][r * 32];                            \
            float4 u = *(const float4*)(mrow + (((2 * q) ^ sw) * 4));          \
            float4 v = *(const float4*)(mrow + (((2 * q + 1) ^ sw) * 4));      \
            split8v(u, v, ah[rg], al[rg]);                                     \
        }                                                                      \
        _Pragma("unroll")                                                      \
        for (int ct = 0; ct < 4; ct++) {                                       \
            int r = wc + ct * 16 + lm, sw = r & 7;                             \
            const _Float16* yrow = &ylds[buf][r * 64];                         \
            f16x8 bh = *(const f16x8*)(yrow + ((q ^ sw) * 8));                 \
            f16x8 bl = *(const f16x8*)(yrow + (((4 + q) ^ sw) * 8));           \
            acc[0][ct] = MFMA(ah[0], bh, acc[0][ct]);                          \
            acc[0][ct] = MFMA(ah[0], bl, acc[0][ct]);                          \
            acc[0][ct] = MFMA(al[0], bh, acc[0][ct]);                          \
            acc[1][ct] = MFMA(ah[1], bh, acc[1][ct]);                          \
            acc[1][ct] = MFMA(ah[1], bl, acc[1][ct]);                          \
            acc[1][ct] = MFMA(al[1], bh, acc[1][ct]);                          \
        }                                                                      \
    } while (0)

    // prologue: chunk 0 in flight (4 glds/wave)
    STAGE(0, 0);
    #pragma unroll
    for (int t = 0; t < 16; t++) {
        if (t < 15) {
            STAGE((t + 1) & 1, t + 1);       // prefetch chunk t+1 (WAR safe:
                                             // buf readers done at last barrier)
            asm volatile("s_waitcnt vmcnt(4)" ::: "memory");   // drain chunk t only
        } else {
            asm volatile("s_waitcnt vmcnt(0)" ::: "memory");
        }
        __builtin_amdgcn_s_barrier();        // all waves' chunk-t data in LDS
        __builtin_amdgcn_sched_barrier(0);   // don't hoist ds_read above wait
        COMPUTE(t & 1);
        __builtin_amdgcn_s_barrier();        // readers done before next overwrite
    }
    #undef STAGE
    #undef COMPUTE

    float* Ap = Apart + (((size_t)(kz * 32 + biz) * 512) + n0 + wr) * 128 + wc;
    #pragma unroll
    for (int rg = 0; rg < 2; rg++)
        #pragma unroll
        for (int ct = 0; ct < 4; ct++)
            #pragma unroll
            for (int rr = 0; rr < 4; rr++)
                Ap[(size_t)(rg * 16 + q * 4 + rr) * 128 + ct * 16 + lm] = acc[rg][ct][rr];
}

// ---------------------------------------------------------------------------
// Reduce 4 K-slices and split to fp16 hi/lo Ain/Aout. float4 per thread.
// Grid 2048 x 256.
// ---------------------------------------------------------------------------
__global__ __launch_bounds__(256) void msg_reduce(const float* __restrict__ Apart,
        _Float16* __restrict__ AinH, _Float16* __restrict__ AinL,
        _Float16* __restrict__ AoutH, _Float16* __restrict__ AoutL) {
    const size_t SL = (size_t)32 * 512 * 128;   // 2,097,152
    size_t idx = ((size_t)blockIdx.x * 256 + threadIdx.x) * 4;
    float4 v0 = *(const float4*)(Apart + idx);
    float4 v1 = *(const float4*)(Apart + idx + SL);
    float4 v2 = *(const float4*)(Apart + idx + 2 * SL);
    float4 v3 = *(const float4*)(Apart + idx + 3 * SL);
    float s[4] = {v0.x + v1.x + v2.x + v3.x, v0.y + v1.y + v2.y + v3.y,
                  v0.z + v1.z + v2.z + v3.z, v0.w + v1.w + v2.w + v3.w};
    int biz = (int)(idx >> 16);
    int rem = (int)(idx & 65535);
    int b = biz >> 1, io = biz & 1;
    size_t d = ((size_t)b << 16) + rem;
    _Float16* Ah = (io ? AoutH : AinH) + d;
    _Float16* Al = (io ? AoutL : AinL) + d;
    #pragma unroll
    for (int j = 0; j < 4; j++) split1(s[j], Ah + j, Al + j);
}

// ---------------------------------------------------------------------------
// Fused gate kernel: gg1 + gate_elem + gg2 in one launch.
// Grid 256, block 256 (4 waves). Block = 32 rows x all 384 gate cols.
// Phase 1: wave w computes preact cols [w*96, w*96+96) for rows 0..31
//   (acc[2][6], K=384 over [Ain|Aout|h]) and writes fp32 preacts to LDS
//   zrt[32][388] (+4 pad -> write banks conflict-free).
// Phase 2 (gg2 layout, wave 16r x 64c): A-operand RH = sigma(r_pre+b_r)*h
//   built on the fly from LDS + hcur (bit-identical to the old RH path),
//   B = Wt1; epilogue reads z/t preacts from LDS, writes hn directly.
// Eliminates: ZRT global (8.4 MB w + 8.4 r), RH global (8.4 w + 8.4 r),
// one launch + serialization bubble per step. Numerics bit-identical.
// ---------------------------------------------------------------------------
__global__ __launch_bounds__(256) void gate_fused(
        const _Float16* __restrict__ AinH, const _Float16* __restrict__ AinL,
        const _Float16* __restrict__ AoutH, const _Float16* __restrict__ AoutL,
        const _Float16* __restrict__ hHi, const _Float16* __restrict__ hLo,
        const _Float16* __restrict__ WzrtH, const _Float16* __restrict__ WzrtL,
        const _Float16* __restrict__ Wt1h, const _Float16* __restrict__ Wt1l,
        const float* __restrict__ hcur,
        const float* __restrict__ b_z, const float* __restrict__ b_r,
        const float* __restrict__ b_t,
        float* __restrict__ hnF, _Float16* __restrict__ hnH, _Float16* __restrict__ hnL) {
    __shared__ float zrt[32][388];            // 49.7 KB, +4 pad de-conflicts
    const int tid = threadIdx.x;
    const int row0 = blockIdx.x * 32;
    const int w = tid >> 6, l = tid & 63;
    const int lm = l & 15, q = l >> 4;
    f32x4 zero = {0.f, 0.f, 0.f, 0.f};

    // ---- phase 1: preacts for cols w*96 .. w*96+96 ----
    {
        const int wc1 = w * 96;
        f32x4 acc[2][6];
        #pragma unroll
        for (int i = 0; i < 2; i++)
            #pragma unroll
            for (int j = 0; j < 6; j++) acc[i][j] = zero;
        const size_t rA0 = (size_t)(row0 + lm) * 128 + q * 8;
        const size_t rA1 = rA0 + 16 * 128;
        const size_t woff = (size_t)(wc1 + lm) * 384 + q * 8;
        #pragma unroll
        for (int ph = 0; ph < 3; ph++) {
            const _Float16* Xh = (ph == 0) ? AinH : (ph == 1) ? AoutH : hHi;
            const _Float16* Xl = (ph == 0) ? AinL : (ph == 1) ? AoutL : hLo;
            #pragma unroll
            for (int ki = 0; ki < 4; ki++) {
                const int kc = ki * 32;
                f16x8 a0h = *(const f16x8*)(Xh + rA0 + kc);
                f16x8 a0l = *(const f16x8*)(Xl + rA0 + kc);
                f16x8 a1h = *(const f16x8*)(Xh + rA1 + kc);
                f16x8 a1l = *(const f16x8*)(Xl + rA1 + kc);
                const int kg = ph * 128 + kc;
                #pragma unroll
                for (int ct = 0; ct < 6; ct++) {
                    f16x8 bh = *(const f16x8*)(WzrtH + woff + (size_t)(ct * 16) * 384 + kg);
                    f16x8 bl = *(const f16x8*)(WzrtL + woff + (size_t)(ct * 16) * 384 + kg);
                    acc[0][ct] = MFMA(a0h, bh, acc[0][ct]);
                    acc[0][ct] = MFMA(a0h, bl, acc[0][ct]);
                    acc[0][ct] = MFMA(a0l, bh, acc[0][ct]);
                    acc[1][ct] = MFMA(a1h, bh, acc[1][ct]);
                    acc[1][ct] = MFMA(a1h, bl, acc[1][ct]);
                    acc[1][ct] = MFMA(a1l, bh, acc[1][ct]);
                }
            }
        }
        #pragma unroll
        for (int rg = 0; rg < 2; rg++)
            #pragma unroll
            for (int ct = 0; ct < 6; ct++)
                #pragma unroll
                for (int rr = 0; rr < 4; rr++)
                    zrt[rg * 16 + q * 4 + rr][wc1 + ct * 16 + lm] = acc[rg][ct][rr];
    }
    __syncthreads();

    // ---- phase 2: gg2 with LDS preacts; RH built on the fly ----
    {
        const int wr2 = (w & 1) * 16, wc2 = (w >> 1) * 64;
        f32x4 acc2[4] = {zero, zero, zero, zero};
        const int arow = wr2 + lm;                    // local A row 0..31
        const size_t woff2 = (size_t)(wc2 + lm) * 128 + q * 8;
        #pragma unroll
        for (int ki = 0; ki < 4; ki++) {
            const int kc = ki * 32;
            const int k0 = kc + q * 8;
            float rh[8];
            #pragma unroll
            for (int j = 0; j < 8; j++) {
                int k = k0 + j;
                float rp = zrt[arow][128 + k] + b_r[k];
                float r = 1.0f / (1.0f + expf(-rp));
                rh[j] = r * hcur[(size_t)(row0 + arow) * 128 + k];
            }
            float4 u = make_float4(rh[0], rh[1], rh[2], rh[3]);
            float4 v = make_float4(rh[4], rh[5], rh[6], rh[7]);
            f16x8 ah, al;
            split8v(u, v, ah, al);
            #pragma unroll
            for (int ct = 0; ct < 4; ct++) {
                f16x8 bh = *(const f16x8*)(Wt1h + woff2 + (size_t)(ct * 16) * 128 + kc);
                f16x8 bl = *(const f16x8*)(Wt1l + woff2 + (size_t)(ct * 16) * 128 + kc);
                acc2[ct] = MFMA(ah, bh, acc2[ct]);
                acc2[ct] = MFMA(ah, bl, acc2[ct]);
                acc2[ct] = MFMA(al, bh, acc2[ct]);
            }
        }
        #pragma unroll
        for (int ct = 0; ct < 4; ct++)
            #pragma unroll
            for (int rr = 0; rr < 4; rr++) {
                int lrow = wr2 + q * 4 + rr;
                int col = wc2 + ct * 16 + lm;
                float tp = acc2[ct][rr] + zrt[lrow][256 + col] + b_t[col];
                float hhat = tanhf(tp);
                float zp = zrt[lrow][col] + b_z[col];
                float z = 1.0f / (1.0f + expf(-zp));
                size_t d = (size_t)(row0 + lrow) * 128 + col;
                float hv = hcur[d];
                float hn = (1.0f - z) * hv + z * hhat;
                hnF[d] = hn;
                split1(hn, hnH + d, hnL + d);
            }
    }
}

// ---------------------------------------------------------------------------
// MFMA readout: feat = tanh([h|a] @ W1 + b1); out = feat@W2 + b2.
// ---------------------------------------------------------------------------
__global__ __launch_bounds__(256) void out_mfma(
        const _Float16* __restrict__ hH, const _Float16* __restrict__ hL,
        const _Float16* __restrict__ W1Th, const _Float16* __restrict__ W1Tl,
        const float* __restrict__ W1, const float* __restrict__ a,
        const float* __restrict__ b1, const float* __restrict__ W2,
        const float* __restrict__ b2, float* __restrict__ out) {
    __shared__ float red[4][16];
    const int tid = threadIdx.x;
    const int row0 = blockIdx.x * 32;
    const int w = tid >> 6, l = tid & 63;
    const int lm = l & 15, q = l >> 4;
    const int wr = (w & 1) * 16, wc = (w >> 1) * 64;
    f32x4 zero = {0.f, 0.f, 0.f, 0.f};
    f32x4 acc[4] = {zero, zero, zero, zero};
    const size_t aoff = (size_t)(row0 + wr + lm) * 128 + q * 8;
    const size_t woff = (size_t)(wc + lm) * 128 + q * 8;
    #pragma unroll
    for (int ki = 0; ki < 4; ki++) {
        const int kc = ki * 32;
        f16x8 ah = *(const f16x8*)(hH + aoff + kc);
        f16x8 al = *(const f16x8*)(hL + aoff + kc);
        #pragma unroll
        for (int ct = 0; ct < 4; ct++) {
            f16x8 bh = *(const f16x8*)(W1Th + woff + (size_t)(ct * 16) * 128 + kc);
            f16x8 bl = *(const f16x8*)(W1Tl + woff + (size_t)(ct * 16) * 128 + kc);
            acc[ct] = MFMA(ah, bh, acc[ct]);
            acc[ct] = MFMA(ah, bl, acc[ct]);
            acc[ct] = MFMA(al, bh, acc[ct]);
        }
    }
    float psum[4] = {0.f, 0.f, 0.f, 0.f};
    #pragma unroll
    for (int ct = 0; ct < 4; ct++) {
        int col = wc + ct * 16 + lm;
        float w2v = W2[col];
        float w1last = W1[128 * 128 + col];
        float b1v = b1[col];
        #pragma unroll
        for (int rr = 0; rr < 4; rr++) {
            int grow = row0 + wr + q * 4 + rr;
            float pre = acc[ct][rr] + a[grow] * w1last + b1v;
            psum[rr] += tanhf(pre) * w2v;
        }
    }
    #pragma unroll
    for (int rr = 0; rr < 4; rr++) {
        float p = psum[rr];
        p += __shfl_xor(p, 1, 64);
        p += __shfl_xor(p, 2, 64);
        p += __shfl_xor(p, 4, 64);
        p += __shfl_xor(p, 8, 64);
        if (lm == 0) red[w][q * 4 + rr] = p;
    }
    __syncthreads();
    if (tid < 32) {
        int r = tid;
        int wsel = (r >> 4) & 1;              // rows 0-15 -> waves 0&2, 16-31 -> 1&3
        out[row0 + r] = red[wsel][r & 15] + red[wsel + 2][r & 15] + b2[0];
    }
}

// ---------------------------------------------------------------------------
extern "C" void kernel_launch(void* const* d_in, const int* in_sizes, int n_in,
                              void* d_out, int out_size, void* d_ws, size_t ws_size,
                              hipStream_t stream) {
    const float* x    = (const float*)d_in[0];
    const float* a    = (const float*)d_in[1];
    const float* m    = (const float*)d_in[2];
    const float* W_in = (const float*)d_in[3];
    const float* b_in = (const float*)d_in[4];
    const float* W_out= (const float*)d_in[5];
    const float* b_out= (const float*)d_in[6];
    const float* W_z  = (const float*)d_in[7];
    const float* b_z  = (const float*)d_in[8];
    const float* W_r  = (const float*)d_in[9];
    const float* b_r  = (const float*)d_in[10];
    const float* W_t  = (const float*)d_in[11];
    const float* b_t  = (const float*)d_in[12];
    const float* W1   = (const float*)d_in[13];
    const float* b1   = (const float*)d_in[14];
    const float* W2   = (const float*)d_in[15];
    const float* b2   = (const float*)d_in[16];
    float* out = (float*)d_out;

    char* p = (char*)d_ws;
    _Float16* WpTh  = (_Float16*)p; p += 262144;
    _Float16* WpTl  = (_Float16*)p; p += 262144;
    float*    bp    = (float*)p;    p += 4096;
    _Float16* WzrtH = (_Float16*)p; p += 294912;
    _Float16* WzrtL = (_Float16*)p; p += 294912;
    _Float16* Wt1h  = (_Float16*)p; p += 32768;
    _Float16* Wt1l  = (_Float16*)p; p += 32768;
    _Float16* W1Th  = (_Float16*)p; p += 32768;
    _Float16* W1Tl  = (_Float16*)p; p += 32768;
    _Float16* YpTh  = (_Float16*)p; p += 16777216;
    _Float16* YpTl  = (_Float16*)p; p += 16777216;
    _Float16* AinH  = (_Float16*)p; p += 2097152;
    _Float16* AinL  = (_Float16*)p; p += 2097152;
    _Float16* AoutH = (_Float16*)p; p += 2097152;
    _Float16* AoutL = (_Float16*)p; p += 2097152;
    float*    hA    = (float*)p;    p += 4194304;
    float*    hB    = (float*)p;    p += 4194304;
    _Float16* hHiA  = (_Float16*)p; p += 2097152;
    _Float16* hLoA  = (_Float16*)p; p += 2097152;
    _Float16* hHiB  = (_Float16*)p; p += 2097152;
    _Float16* hLoB  = (_Float16*)p; p += 2097152;
    float*    Apart = (float*)p;    p += 33554432;   // 4 kz-slices

    prep_kernel<<<5312, 256, 0, stream>>>(x, W_in, b_in, W_out, b_out, W_z, W_r, W_t,
                                          W1, WpTh, WpTl, bp, WzrtH, WzrtL, Wt1h, Wt1l,
                                          hHiA, hLoA, W1Th, W1Tl);

    const float* curF = x;
    const _Float16 *curH = hHiA, *curL = hLoA;
    for (int s = 0; s < NSTEPS; s++) {
        float*    nF = (s & 1) ? hB : hA;
        _Float16* nH = (s & 1) ? hHiA : hHiB;
        _Float16* nL = (s & 1) ? hLoA : hLoB;
        xw_mfma<<<dim3(16, 4, 16), 256, 0, stream>>>(curH, curL, WpTh, WpTl, bp, YpTh, YpTl);
        msg_mfma<<<dim3(512), 512, 0, stream>>>(m, YpTh, YpTl, Apart);
        msg_reduce<<<2048, 256, 0, stream>>>(Apart, AinH, AinL, AoutH, AoutL);
        gate_fused<<<256, 256, 0, stream>>>(AinH, AinL, AoutH, AoutL, curH, curL,
                                            WzrtH, WzrtL, Wt1h, Wt1l, curF,
                                            b_z, b_r, b_t, nF, nH, nL);
        curF = nF; curH = nH; curL = nL;
    }
    out_mfma<<<256, 256, 0, stream>>>(curH, curL, W1Th, W1Tl, W1, a, b1, W2, b2, out);
}

// Round 8
// 696.412 us; speedup vs baseline: 1.1905x; 1.0855x over previous
//
#include <hip/hip_runtime.h>
#include <math.h>

#define BB 16
#define NN 512
#define HH 128
#define EE 4
#define NSTEPS 5
#define ROWS (BB*NN)      // 8192
#define KDIM (NN*EE)      // 2048

typedef _Float16 f16x8 __attribute__((ext_vector_type(8)));
typedef float f32x4 __attribute__((ext_vector_type(4)));

#define MFMA(a,b,c) __builtin_amdgcn_mfma_f32_16x16x32_f16(a, b, c, 0, 0, 0)

__device__ inline void split8v(float4 u, float4 v, f16x8& hi, f16x8& lo) {
    float f[8] = {u.x, u.y, u.z, u.w, v.x, v.y, v.z, v.w};
    #pragma unroll
    for (int i = 0; i < 8; i++) {
        _Float16 h = (_Float16)f[i];
        hi[i] = h;
        lo[i] = (_Float16)(f[i] - (float)h);
    }
}

__device__ inline void split1(float v, _Float16* __restrict__ hp, _Float16* __restrict__ lp) {
    _Float16 h = (_Float16)v;
    *hp = h;
    *lp = (_Float16)(v - (float)h);
}

// async global->LDS, 16B per lane. lds must be wave-uniform base; HW scatters
// lane i at base + i*16.
__device__ __forceinline__ void async16(void* lds, const void* g) {
    __builtin_amdgcn_global_load_lds(
        (const __attribute__((address_space(1))) void*)g,
        (__attribute__((address_space(3))) void*)lds,
        16, 0, 0);
}

// ---------------------------------------------------------------------------
// Prep: split-fp16 transposed weights + split of initial h = x + W1T split.
// ---------------------------------------------------------------------------
__global__ void prep_kernel(const float* __restrict__ x,
                            const float* __restrict__ W_in, const float* __restrict__ b_in,
                            const float* __restrict__ W_out, const float* __restrict__ b_out,
                            const float* __restrict__ W_z, const float* __restrict__ W_r,
                            const float* __restrict__ W_t, const float* __restrict__ W1,
                            _Float16* __restrict__ WpTh, _Float16* __restrict__ WpTl,
                            float* __restrict__ bp,
                            _Float16* __restrict__ WzrtH, _Float16* __restrict__ WzrtL,
                            _Float16* __restrict__ Wt1h, _Float16* __restrict__ Wt1l,
                            _Float16* __restrict__ hHi, _Float16* __restrict__ hLo,
                            _Float16* __restrict__ W1Th, _Float16* __restrict__ W1Tl) {
    int idx = blockIdx.x * 256 + threadIdx.x;
    if (idx < 131072) {                                  // WpT
        int c = idx >> 7, k = idx & 127;
        int io = c >> 9, cc = c & 511, e = cc >> 7, hh = cc & 127;
        const float* W = io ? W_out : W_in;
        split1(W[k * 512 + hh * 4 + e], WpTh + idx, WpTl + idx);
        if (k == 0) bp[c] = (io ? b_out : b_in)[hh * 4 + e];
    } else if (idx < 131072 + 147456) {                  // Wzrt
        int j = idx - 131072;
        int c = j / 384, k = j - c * 384;
        float v;
        if (c < 128)      v = W_z[k * 128 + c];
        else if (c < 256) v = W_r[k * 128 + (c - 128)];
        else              v = (k < 256) ? W_t[k * 128 + (c - 256)] : 0.0f;
        split1(v, WzrtH + j, WzrtL + j);
    } else if (idx < 131072 + 147456 + 16384) {          // Wt1
        int j = idx - 131072 - 147456;
        int c = j >> 7, k = j & 127;
        split1(W_t[(256 + k) * 128 + c], Wt1h + j, Wt1l + j);
    } else if (idx < 131072 + 147456 + 16384 + 1048576) { // split x -> h hi/lo
        int j = idx - 131072 - 147456 - 16384;
        split1(x[j], hHi + j, hLo + j);
    } else if (idx < 131072 + 147456 + 16384 + 1048576 + 16384) { // W1T (k<128 rows)
        int j = idx - (131072 + 147456 + 16384 + 1048576);
        int c = j >> 7, k = j & 127;
        split1(W1[k * 128 + c], W1Th + j, W1Tl + j);
    }
}

// ---------------------------------------------------------------------------
// YpT[b][c][n'] = sum_k WpT[c][k] * h[b*512+n'][k] + bp[c], split-fp16 out.
// Grid (16,4,16); block 64c x 128n, 4 waves (wave 32c x 64n).
// ---------------------------------------------------------------------------
__global__ __launch_bounds__(256) void xw_mfma(
        const _Float16* __restrict__ hHi, const _Float16* __restrict__ hLo,
        const _Float16* __restrict__ WpTh, const _Float16* __restrict__ WpTl,
        const float* __restrict__ bp,
        _Float16* __restrict__ YpTh, _Float16* __restrict__ YpTl) {
    const int tid = threadIdx.x;
    const int c0 = blockIdx.x * 64;
    const int n0 = blockIdx.y * 128;
    const int b  = blockIdx.z;
    const int w = tid >> 6, l = tid & 63;
    const int lm = l & 15, q = l >> 4;
    const int wr = (w & 1) * 32, wc = (w >> 1) * 64;
    f32x4 zero = {0.f, 0.f, 0.f, 0.f};
    f32x4 acc[2][4];
    #pragma unroll
    for (int i = 0; i < 2; i++)
        #pragma unroll
        for (int j = 0; j < 4; j++) acc[i][j] = zero;
    const size_t aoff = (size_t)(c0 + wr + lm) * 128 + q * 8;
    const size_t boff = (size_t)(b * 512 + n0 + wc + lm) * 128 + q * 8;
    #pragma unroll
    for (int ki = 0; ki < 4; ki++) {
        const int kc = ki * 32;
        f16x8 a0h = *(const f16x8*)(WpTh + aoff + kc);
        f16x8 a0l = *(const f16x8*)(WpTl + aoff + kc);
        f16x8 a1h = *(const f16x8*)(WpTh + aoff + 16 * 128 + kc);
        f16x8 a1l = *(const f16x8*)(WpTl + aoff + 16 * 128 + kc);
        #pragma unroll
        for (int ct = 0; ct < 4; ct++) {
            f16x8 bh = *(const f16x8*)(hHi + boff + (size_t)(ct * 16) * 128 + kc);
            f16x8 bl = *(const f16x8*)(hLo + boff + (size_t)(ct * 16) * 128 + kc);
            acc[0][ct] = MFMA(a0h, bh, acc[0][ct]);
            acc[0][ct] = MFMA(a0h, bl, acc[0][ct]);
            acc[0][ct] = MFMA(a0l, bh, acc[0][ct]);
            acc[1][ct] = MFMA(a1h, bh, acc[1][ct]);
            acc[1][ct] = MFMA(a1h, bl, acc[1][ct]);
            acc[1][ct] = MFMA(a1l, bh, acc[1][ct]);
        }
    }
    #pragma unroll
    for (int rg = 0; rg < 2; rg++)
        #pragma unroll
        for (int rr = 0; rr < 4; rr++) {
            int c = c0 + wr + rg * 16 + q * 4 + rr;
            float bias = bp[c];
            size_t d = ((size_t)b * 1024 + c) * 512 + n0 + wc + lm;
            #pragma unroll
            for (int ct = 0; ct < 4; ct++) {
                float v = acc[rg][ct][rr] + bias;
                split1(v, YpTh + d + ct * 16, YpTl + d + ct * 16);
            }
        }
}

// ---------------------------------------------------------------------------
// Einsum (v5, the 787-µs config, verbatim). Each block: (b, io, kz),
// n-tile 128 x h 128, K = 512 as 16 chunks of 32. 512-thread blocks (8 waves:
// 4 n-rowgroups x 2 h-colgroups); m staged once per block via global_load_lds;
// LDS: per buffer m [128][32] fp32 16 KB + Y [128][64] f16 16 KB, x2 = 64 KB
// -> 2 blocks/CU, 16 waves/CU, 512 blocks = 1 round. Counted vmcnt(4)
// depth-1, one sched_barrier after s_barrier, XOR-swizzle both tiles via
// pre-swizzled source (0 conflicts). 4 blocks/Y-slab share wg%8 -> same XCD.
// ---------------------------------------------------------------------------
__global__ __launch_bounds__(512, 4) void msg_mfma(const float* __restrict__ m,
        const _Float16* __restrict__ YpTh, const _Float16* __restrict__ YpTl,
        float* __restrict__ Apart) {
    __shared__ float    mlds[2][128 * 32];    // 16 KB per buffer
    __shared__ _Float16 ylds[2][128 * 64];    // 16 KB per buffer: row = [32 hi | 32 lo]

    const int tid = threadIdx.x;
    const int w = tid >> 6, l = tid & 63;
    const int lm = l & 15, q = l >> 4;
    const int wr = (w & 3) * 32;              // 4 n-row groups
    const int wc = (w >> 2) * 64;             // 2 h-col groups

    // XCD-aware decode of flat blockIdx.x in [0,512)
    const int wg = blockIdx.x;
    const int xcd = wg & 7;
    const int s8  = wg >> 3;          // [0,64)
    const int gi  = s8 >> 2;          // [0,16) group-within-xcd
    const int t4  = s8 & 3;           // n-tile within group
    const int g   = gi * 8 + xcd;     // [0,128) = (biz, kz)
    const int kz  = g & 3;
    const int biz = g >> 2;
    const int b = biz >> 1, io = biz & 1;
    const int n0 = t4 * 128;

    const float*    mg  = m    + (size_t)(b * 512 + n0) * 4096 + io * 2048 + kz * 512;
    const _Float16* yhg = YpTh + (size_t)(b * 1024 + io * 512 + kz * 128) * 512;
    const _Float16* ylg = YpTl + (size_t)(b * 1024 + io * 512 + kz * 128) * 512;

    f32x4 zero = {0.f, 0.f, 0.f, 0.f};
    f32x4 acc[2][4];
    #pragma unroll
    for (int i = 0; i < 2; i++)
        #pragma unroll
        for (int j = 0; j < 4; j++) acc[i][j] = zero;

    // stage K-chunk kt into buffer buf: 4 glds per wave (2 m + 2 Y)
    #define STAGE(buf, kt) do {                                                \
        _Pragma("unroll")                                                      \
        for (int j = 0; j < 2; j++) {      /* m: 128 rows x 128B */            \
            int gi2 = (w * 2 + j) * 64 + l;                                    \
            int r = gi2 >> 3, pg = gi2 & 7;                                    \
            int lg = pg ^ (r & 7);                                             \
            async16(&mlds[buf][(w * 2 + j) * 256],                             \
                    mg + (size_t)r * 4096 + (size_t)(kt) * 32 + lg * 4);       \
        }                                                                      \
        _Pragma("unroll")                                                      \
        for (int j = 0; j < 2; j++) {      /* Y: 128 rows x 128B (hi|lo) */    \
            int gi2 = (w * 2 + j) * 64 + l;                                    \
            int r = gi2 >> 3, pg = gi2 & 7;                                    \
            int lg = pg ^ (r & 7);                                             \
            const _Float16* src = (lg < 4 ? yhg : ylg)                         \
                + (size_t)r * 512 + (size_t)(kt) * 32 + (lg & 3) * 8;          \
            async16(&ylds[buf][(w * 2 + j) * 512], src);                       \
        }                                                                      \
    } while (0)

    #define COMPUTE(buf) do {                                                  \
        f16x8 ah[2], al[2];                                                    \
        _Pragma("unroll")                                                      \
        for (int rg = 0; rg < 2; rg++) {                                       \
            int r = wr + rg * 16 + lm, sw = r & 7;                             \
            const float* mrow = &mlds[buf][r * 32];                            \
            float4 u = *(const float4*)(mrow + (((2 * q) ^ sw) * 4));          \
            float4 v = *(const float4*)(mrow + (((2 * q + 1) ^ sw) * 4));      \
            split8v(u, v, ah[rg], al[rg]);                                     \
        }                                                                      \
        _Pragma("unroll")                                                      \
        for (int ct = 0; ct < 4; ct++) {                                       \
            int r = wc + ct * 16 + lm, sw = r & 7;                             \
            const _Float16* yrow = &ylds[buf][r * 64];                         \
            f16x8 bh = *(const f16x8*)(yrow + ((q ^ sw) * 8));                 \
            f16x8 bl = *(const f16x8*)(yrow + (((4 + q) ^ sw) * 8));           \
            acc[0][ct] = MFMA(ah[0], bh, acc[0][ct]);                          \
            acc[0][ct] = MFMA(ah[0], bl, acc[0][ct]);                          \
            acc[0][ct] = MFMA(al[0], bh, acc[0][ct]);                          \
            acc[1][ct] = MFMA(ah[1], bh, acc[1][ct]);                          \
            acc[1][ct] = MFMA(ah[1], bl, acc[1][ct]);                          \
            acc[1][ct] = MFMA(al[1], bh, acc[1][ct]);                          \
        }                                                                      \
    } while (0)

    // prologue: chunk 0 in flight (4 glds/wave)
    STAGE(0, 0);
    #pragma unroll
    for (int t = 0; t < 16; t++) {
        if (t < 15) {
            STAGE((t + 1) & 1, t + 1);       // prefetch chunk t+1 (WAR safe:
                                             // buf readers done at last barrier)
            asm volatile("s_waitcnt vmcnt(4)" ::: "memory");   // drain chunk t only
        } else {
            asm volatile("s_waitcnt vmcnt(0)" ::: "memory");
        }
        __builtin_amdgcn_s_barrier();        // all waves' chunk-t data in LDS
        __builtin_amdgcn_sched_barrier(0);   // don't hoist ds_read above wait
        COMPUTE(t & 1);
        __builtin_amdgcn_s_barrier();        // readers done before next overwrite
    }
    #undef STAGE
    #undef COMPUTE

    float* Ap = Apart + (((size_t)(kz * 32 + biz) * 512) + n0 + wr) * 128 + wc;
    #pragma unroll
    for (int rg = 0; rg < 2; rg++)
        #pragma unroll
        for (int ct = 0; ct < 4; ct++)
            #pragma unroll
            for (int rr = 0; rr < 4; rr++)
                Ap[(size_t)(rg * 16 + q * 4 + rr) * 128 + ct * 16 + lm] = acc[rg][ct][rr];
}

// ---------------------------------------------------------------------------
// Fused gate kernel v2: slice-reduce + gg1 + gate_elem + gg2 in one launch.
// Grid 256, block 256 (4 waves). Block = 32 rows x all 384 gate cols.
// Phase 0: cooperatively read the 4 kz-slices of Apart fp32 for this block's
//   A-tile (2 io x 32 rows x 128 k), sum left-to-right (same order as the
//   old msg_reduce), split1, store to LDS Ald[io][hi/lo][32][132] (+4 pad).
//   Replaces the msg_reduce kernel; bit-identical A values.
// Phase 1: wave w computes preact cols [w*96, w*96+96) (acc[2][6], K=384
//   over [Ain|Aout|h]); A-frags for ph<2 from Ald, h from global. Writes
//   fp32 preacts to LDS zrt[32][388].
// Phase 2 (gg2 layout): RH = sigma(r_pre+b_r)*h built on the fly; B = Wt1;
//   epilogue reads z/t preacts from LDS, writes hn. Numerics bit-identical.
// LDS: zrt 49.7 KB + Ald 33.8 KB = 83.5 KB.
// ---------------------------------------------------------------------------
__global__ __launch_bounds__(256) void gate_fused(
        const float* __restrict__ Apart,
        const _Float16* __restrict__ hHi, const _Float16* __restrict__ hLo,
        const _Float16* __restrict__ WzrtH, const _Float16* __restrict__ WzrtL,
        const _Float16* __restrict__ Wt1h, const _Float16* __restrict__ Wt1l,
        const float* __restrict__ hcur,
        const float* __restrict__ b_z, const float* __restrict__ b_r,
        const float* __restrict__ b_t,
        float* __restrict__ hnF, _Float16* __restrict__ hnH, _Float16* __restrict__ hnL) {
    __shared__ float zrt[32][388];            // 49.7 KB
    __shared__ _Float16 Ald[2][2][32][132];   // [io][hi/lo][row][k+pad] 33.8 KB
    const int tid = threadIdx.x;
    const int row0 = blockIdx.x * 32;
    const int w = tid >> 6, l = tid & 63;
    const int lm = l & 15, q = l >> 4;
    const int b = row0 >> 9;
    const int n_base = row0 & 511;
    f32x4 zero = {0.f, 0.f, 0.f, 0.f};

    // ---- phase 0: reduce 4 kz-slices -> split -> LDS ----
    {
        const size_t SL = (size_t)32 * 512 * 128;   // kz-slice stride
        #pragma unroll
        for (int i = 0; i < 8; i++) {               // 2048 float4s / 256 thr
            int e4 = i * 256 + tid;
            int io = e4 >> 10;
            int rem = e4 & 1023;
            int lrow = rem >> 5;
            int k = (rem & 31) * 4;
            const float* A = Apart +
                (((size_t)(b * 2 + io) * 512 + n_base + lrow) * 128 + k);
            float4 v0 = *(const float4*)A;
            float4 v1 = *(const float4*)(A + SL);
            float4 v2 = *(const float4*)(A + 2 * SL);
            float4 v3 = *(const float4*)(A + 3 * SL);
            float s0 = v0.x + v1.x + v2.x + v3.x;
            float s1 = v0.y + v1.y + v2.y + v3.y;
            float s2 = v0.z + v1.z + v2.z + v3.z;
            float s3 = v0.w + v1.w + v2.w + v3.w;
            split1(s0, &Ald[io][0][lrow][k],     &Ald[io][1][lrow][k]);
            split1(s1, &Ald[io][0][lrow][k + 1], &Ald[io][1][lrow][k + 1]);
            split1(s2, &Ald[io][0][lrow][k + 2], &Ald[io][1][lrow][k + 2]);
            split1(s3, &Ald[io][0][lrow][k + 3], &Ald[io][1][lrow][k + 3]);
        }
    }
    __syncthreads();

    // ---- phase 1: preacts for cols w*96 .. w*96+96 ----
    {
        const int wc1 = w * 96;
        f32x4 acc[2][6];
        #pragma unroll
        for (int i = 0; i < 2; i++)
            #pragma unroll
            for (int j = 0; j < 6; j++) acc[i][j] = zero;
        const size_t rA0 = (size_t)(row0 + lm) * 128 + q * 8;
        const size_t rA1 = rA0 + 16 * 128;
        const size_t woff = (size_t)(wc1 + lm) * 384 + q * 8;
        #pragma unroll
        for (int ph = 0; ph < 3; ph++) {
            #pragma unroll
            for (int ki = 0; ki < 4; ki++) {
                const int kc = ki * 32;
                f16x8 a0h, a0l, a1h, a1l;
                if (ph < 2) {
                    a0h = *(const f16x8*)(&Ald[ph][0][lm][q * 8 + kc]);
                    a0l = *(const f16x8*)(&Ald[ph][1][lm][q * 8 + kc]);
                    a1h = *(const f16x8*)(&Ald[ph][0][16 + lm][q * 8 + kc]);
                    a1l = *(const f16x8*)(&Ald[ph][1][16 + lm][q * 8 + kc]);
                } else {
                    a0h = *(const f16x8*)(hHi + rA0 + kc);
                    a0l = *(const f16x8*)(hLo + rA0 + kc);
                    a1h = *(const f16x8*)(hHi + rA1 + kc);
                    a1l = *(const f16x8*)(hLo + rA1 + kc);
                }
                const int kg = ph * 128 + kc;
                #pragma unroll
                for (int ct = 0; ct < 6; ct++) {
                    f16x8 bh = *(const f16x8*)(WzrtH + woff + (size_t)(ct * 16) * 384 + kg);
                    f16x8 bl = *(const f16x8*)(WzrtL + woff + (size_t)(ct * 16) * 384 + kg);
                    acc[0][ct] = MFMA(a0h, bh, acc[0][ct]);
                    acc[0][ct] = MFMA(a0h, bl, acc[0][ct]);
                    acc[0][ct] = MFMA(a0l, bh, acc[0][ct]);
                    acc[1][ct] = MFMA(a1h, bh, acc[1][ct]);
                    acc[1][ct] = MFMA(a1h, bl, acc[1][ct]);
                    acc[1][ct] = MFMA(a1l, bh, acc[1][ct]);
                }
            }
        }
        #pragma unroll
        for (int rg = 0; rg < 2; rg++)
            #pragma unroll
            for (int ct = 0; ct < 6; ct++)
                #pragma unroll
                for (int rr = 0; rr < 4; rr++)
                    zrt[rg * 16 + q * 4 + rr][wc1 + ct * 16 + lm] = acc[rg][ct][rr];
    }
    __syncthreads();

    // ---- phase 2: gg2 with LDS preacts; RH built on the fly ----
    {
        const int wr2 = (w & 1) * 16, wc2 = (w >> 1) * 64;
        f32x4 acc2[4] = {zero, zero, zero, zero};
        const int arow = wr2 + lm;                    // local A row 0..31
        const size_t woff2 = (size_t)(wc2 + lm) * 128 + q * 8;
        #pragma unroll
        for (int ki = 0; ki < 4; ki++) {
            const int kc = ki * 32;
            const int k0 = kc + q * 8;
            float rh[8];
            #pragma unroll
            for (int j = 0; j < 8; j++) {
                int k = k0 + j;
                float rp = zrt[arow][128 + k] + b_r[k];
                float r = 1.0f / (1.0f + expf(-rp));
                rh[j] = r * hcur[(size_t)(row0 + arow) * 128 + k];
            }
            float4 u = make_float4(rh[0], rh[1], rh[2], rh[3]);
            float4 v = make_float4(rh[4], rh[5], rh[6], rh[7]);
            f16x8 ah, al;
            split8v(u, v, ah, al);
            #pragma unroll
            for (int ct = 0; ct < 4; ct++) {
                f16x8 bh = *(const f16x8*)(Wt1h + woff2 + (size_t)(ct * 16) * 128 + kc);
                f16x8 bl = *(const f16x8*)(Wt1l + woff2 + (size_t)(ct * 16) * 128 + kc);
                acc2[ct] = MFMA(ah, bh, acc2[ct]);
                acc2[ct] = MFMA(ah, bl, acc2[ct]);
                acc2[ct] = MFMA(al, bh, acc2[ct]);
            }
        }
        #pragma unroll
        for (int ct = 0; ct < 4; ct++)
            #pragma unroll
            for (int rr = 0; rr < 4; rr++) {
                int lrow = wr2 + q * 4 + rr;
                int col = wc2 + ct * 16 + lm;
                float tp = acc2[ct][rr] + zrt[lrow][256 + col] + b_t[col];
                float hhat = tanhf(tp);
                float zp = zrt[lrow][col] + b_z[col];
                float z = 1.0f / (1.0f + expf(-zp));
                size_t d = (size_t)(row0 + lrow) * 128 + col;
                float hv = hcur[d];
                float hn = (1.0f - z) * hv + z * hhat;
                hnF[d] = hn;
                split1(hn, hnH + d, hnL + d);
            }
    }
}

// ---------------------------------------------------------------------------
// MFMA readout: feat = tanh([h|a] @ W1 + b1); out = feat@W2 + b2.
// ---------------------------------------------------------------------------
__global__ __launch_bounds__(256) void out_mfma(
        const _Float16* __restrict__ hH, const _Float16* __restrict__ hL,
        const _Float16* __restrict__ W1Th, const _Float16* __restrict__ W1Tl,
        const float* __restrict__ W1, const float* __restrict__ a,
        const float* __restrict__ b1, const float* __restrict__ W2,
        const float* __restrict__ b2, float* __restrict__ out) {
    __shared__ float red[4][16];
    const int tid = threadIdx.x;
    const int row0 = blockIdx.x * 32;
    const int w = tid >> 6, l = tid & 63;
    const int lm = l & 15, q = l >> 4;
    const int wr = (w & 1) * 16, wc = (w >> 1) * 64;
    f32x4 zero = {0.f, 0.f, 0.f, 0.f};
    f32x4 acc[4] = {zero, zero, zero, zero};
    const size_t aoff = (size_t)(row0 + wr + lm) * 128 + q * 8;
    const size_t woff = (size_t)(wc + lm) * 128 + q * 8;
    #pragma unroll
    for (int ki = 0; ki < 4; ki++) {
        const int kc = ki * 32;
        f16x8 ah = *(const f16x8*)(hH + aoff + kc);
        f16x8 al = *(const f16x8*)(hL + aoff + kc);
        #pragma unroll
        for (int ct = 0; ct < 4; ct++) {
            f16x8 bh = *(const f16x8*)(W1Th + woff + (size_t)(ct * 16) * 128 + kc);
            f16x8 bl = *(const f16x8*)(W1Tl + woff + (size_t)(ct * 16) * 128 + kc);
            acc[ct] = MFMA(ah, bh, acc[ct]);
            acc[ct] = MFMA(ah, bl, acc[ct]);
            acc[ct] = MFMA(al, bh, acc[ct]);
        }
    }
    float psum[4] = {0.f, 0.f, 0.f, 0.f};
    #pragma unroll
    for (int ct = 0; ct < 4; ct++) {
        int col = wc + ct * 16 + lm;
        float w2v = W2[col];
        float w1last = W1[128 * 128 + col];
        float b1v = b1[col];
        #pragma unroll
        for (int rr = 0; rr < 4; rr++) {
            int grow = row0 + wr + q * 4 + rr;
            float pre = acc[ct][rr] + a[grow] * w1last + b1v;
            psum[rr] += tanhf(pre) * w2v;
        }
    }
    #pragma unroll
    for (int rr = 0; rr < 4; rr++) {
        float p = psum[rr];
        p += __shfl_xor(p, 1, 64);
        p += __shfl_xor(p, 2, 64);
        p += __shfl_xor(p, 4, 64);
        p += __shfl_xor(p, 8, 64);
        if (lm == 0) red[w][q * 4 + rr] = p;
    }
    __syncthreads();
    if (tid < 32) {
        int r = tid;
        int wsel = (r >> 4) & 1;              // rows 0-15 -> waves 0&2, 16-31 -> 1&3
        out[row0 + r] = red[wsel][r & 15] + red[wsel + 2][r & 15] + b2[0];
    }
}

// ---------------------------------------------------------------------------
extern "C" void kernel_launch(void* const* d_in, const int* in_sizes, int n_in,
                              void* d_out, int out_size, void* d_ws, size_t ws_size,
                              hipStream_t stream) {
    const float* x    = (const float*)d_in[0];
    const float* a    = (const float*)d_in[1];
    const float* m    = (const float*)d_in[2];
    const float* W_in = (const float*)d_in[3];
    const float* b_in = (const float*)d_in[4];
    const float* W_out= (const float*)d_in[5];
    const float* b_out= (const float*)d_in[6];
    const float* W_z  = (const float*)d_in[7];
    const float* b_z  = (const float*)d_in[8];
    const float* W_r  = (const float*)d_in[9];
    const float* b_r  = (const float*)d_in[10];
    const float* W_t  = (const float*)d_in[11];
    const float* b_t  = (const float*)d_in[12];
    const float* W1   = (const float*)d_in[13];
    const float* b1   = (const float*)d_in[14];
    const float* W2   = (const float*)d_in[15];
    const float* b2   = (const float*)d_in[16];
    float* out = (float*)d_out;

    char* p = (char*)d_ws;
    _Float16* WpTh  = (_Float16*)p; p += 262144;
    _Float16* WpTl  = (_Float16*)p; p += 262144;
    float*    bp    = (float*)p;    p += 4096;
    _Float16* WzrtH = (_Float16*)p; p += 294912;
    _Float16* WzrtL = (_Float16*)p; p += 294912;
    _Float16* Wt1h  = (_Float16*)p; p += 32768;
    _Float16* Wt1l  = (_Float16*)p; p += 32768;
    _Float16* W1Th  = (_Float16*)p; p += 32768;
    _Float16* W1Tl  = (_Float16*)p; p += 32768;
    _Float16* YpTh  = (_Float16*)p; p += 16777216;
    _Float16* YpTl  = (_Float16*)p; p += 16777216;
    float*    hA    = (float*)p;    p += 4194304;
    float*    hB    = (float*)p;    p += 4194304;
    _Float16* hHiA  = (_Float16*)p; p += 2097152;
    _Float16* hLoA  = (_Float16*)p; p += 2097152;
    _Float16* hHiB  = (_Float16*)p; p += 2097152;
    _Float16* hLoB  = (_Float16*)p; p += 2097152;
    float*    Apart = (float*)p;    p += 33554432;   // 4 kz-slices

    prep_kernel<<<5312, 256, 0, stream>>>(x, W_in, b_in, W_out, b_out, W_z, W_r, W_t,
                                          W1, WpTh, WpTl, bp, WzrtH, WzrtL, Wt1h, Wt1l,
                                          hHiA, hLoA, W1Th, W1Tl);

    const float* curF = x;
    const _Float16 *curH = hHiA, *curL = hLoA;
    for (int s = 0; s < NSTEPS; s++) {
        float*    nF = (s & 1) ? hB : hA;
        _Float16* nH = (s & 1) ? hHiA : hHiB;
        _Float16* nL = (s & 1) ? hLoA : hLoB;
        xw_mfma<<<dim3(16, 4, 16), 256, 0, stream>>>(curH, curL, WpTh, WpTl, bp, YpTh, YpTl);
        msg_mfma<<<dim3(512), 512, 0, stream>>>(m, YpTh, YpTl, Apart);
        gate_fused<<<256, 256, 0, stream>>>(Apart, curH, curL,
                                            WzrtH, WzrtL, Wt1h, Wt1l, curF,
                                            b_z, b_r, b_t, nF, nH, nL);
        curF = nF; curH = nH; curL = nL;
    }
    out_mfma<<<256, 256, 0, stream>>>(curH, curL, W1Th, W1Tl, W1, a, b1, W2, b2, out);
}